// Round 1
// baseline (1149.503 us; speedup 1.0000x reference)
//
#include <hip/hip_runtime.h>
#include <math.h>

#define N_NODES 50000
#define N_EDGES 600000

typedef __attribute__((ext_vector_type(8))) short bf16x8;
typedef __attribute__((ext_vector_type(4))) float f32x4;

__device__ __forceinline__ unsigned short f2bf(float f){
  union { float f; unsigned int u; } v; v.f = f;
  unsigned int u = v.u;
  unsigned int r = (u + 0x7fffu + ((u >> 16) & 1u)) >> 16;
  return (unsigned short)r;
}
__device__ __forceinline__ float gelu_f(float x){
  return 0.5f * x * (1.0f + erff(x * 0.70710678118654752440f));
}

// ---------------- weight packing: W[K][N] fp32 -> bf16 fragments ----------------
// out[((kt*N + n)*4 + q)*8 + j] = bf16(W[(kt*32 + q*8 + j)*N + n])
// lane (n=l&15 (+nt*16), q=l>>4) loads 8 contiguous bf16 = 1 dwordx4.
__global__ void pack_kernel(const float* __restrict__ W, unsigned short* __restrict__ out,
                            int K, int N){
  int id = blockIdx.x * 256 + threadIdx.x;
  if (id >= K * N) return;
  int j = id & 7;
  int q = (id >> 3) & 3;
  int rest = id >> 5;
  int n = rest % N;
  int kt = rest / N;
  int k = kt * 32 + q * 8 + j;
  out[id] = f2bf(W[(size_t)k * N + n]);
}

// ---------------- LN1: h = LN(x)*g+b, stored bf16 ----------------
__global__ __launch_bounds__(256) void ln1_kernel(const float* __restrict__ x,
                                                  const float* __restrict__ g,
                                                  const float* __restrict__ b,
                                                  unsigned short* __restrict__ h_bf, int n){
  int row = blockIdx.x * 4 + (threadIdx.x >> 6);
  if (row >= n) return;
  int lane = threadIdx.x & 63;
  const float* xr = x + (size_t)row * 128;
  float2 v = *(const float2*)(xr + lane * 2);
  float s = v.x + v.y;
  float s2 = v.x * v.x + v.y * v.y;
#pragma unroll
  for (int off = 32; off; off >>= 1){ s += __shfl_xor(s, off); s2 += __shfl_xor(s2, off); }
  float mu = s * (1.f / 128.f);
  float var = s2 * (1.f / 128.f) - mu * mu;
  float rs = rsqrtf(var + 1e-5f);
  int c = lane * 2;
  ushort2 o;
  o.x = f2bf((v.x - mu) * rs * g[c] + b[c]);
  o.y = f2bf((v.y - mu) * rs * g[c + 1] + b[c + 1]);
  *(ushort2*)(h_bf + (size_t)row * 128 + c) = o;
}

// ---------------- fused edge kernel: 64 edges/block ----------------
__global__ __launch_bounds__(256, 2) void edge_kernel(
    const unsigned short* __restrict__ h_bf,
    const int* __restrict__ esrc, const int* __restrict__ edst,
    const float* __restrict__ emb,
    const unsigned short* __restrict__ Wm1p, const float* __restrict__ bm1,
    const unsigned short* __restrict__ Wm2p, const float* __restrict__ bm2,
    const unsigned short* __restrict__ Wg1p, const float* __restrict__ bg1,
    const float* __restrict__ wg2, const float* __restrict__ bg2,
    float* __restrict__ out_e, float* __restrict__ agg, float* __restrict__ deg)
{
  // A = [hd(0:128) | hs(128:256) | emb(256:320)], bf16, padded stride 328 (bank-safe)
  __shared__ unsigned short smA[64][328];
  __shared__ unsigned short smT[64][136];
  __shared__ float smGate[64];
  __shared__ int smDst[64];

  const int t = threadIdx.x;
  const int e0 = blockIdx.x * 64;

  if (t < 64){
    int d = edst[e0 + t];
    smDst[t] = d;
    atomicAdd(&deg[d], 1.0f);
  }
  {
    const int r = t >> 2, i = t & 3;      // 4 threads per edge row, 32 cols each
    const int e = e0 + r;
    const int ds = edst[e], ss = esrc[e];
    const uint4* hdp = (const uint4*)(h_bf + (size_t)ds * 128 + i * 32);
    const uint4* hsp = (const uint4*)(h_bf + (size_t)ss * 128 + i * 32);
    uint4* a0 = (uint4*)&smA[r][i * 32];
    uint4* a1 = (uint4*)&smA[r][128 + i * 32];
#pragma unroll
    for (int k2 = 0; k2 < 4; k2++){ a0[k2] = hdp[k2]; a1[k2] = hsp[k2]; }
    const float4* ep = (const float4*)(emb + (size_t)e * 64 + i * 16);
#pragma unroll
    for (int k2 = 0; k2 < 4; k2++){
      float4 f = ep[k2];
      ushort4 u; u.x = f2bf(f.x); u.y = f2bf(f.y); u.z = f2bf(f.z); u.w = f2bf(f.w);
      *(ushort4*)&smA[r][256 + i * 16 + k2 * 4] = u;
    }
  }
  __syncthreads();

  const int wave = t >> 6, lane = t & 63;
  const int q = lane >> 4, ln = lane & 15;
  const int arow = wave * 16 + ln;  // this wave owns edge rows [wave*16, wave*16+16)
  const int kq = q * 8;

  // ---------- gate path: sigmoid( gelu(A[:,0:320]@Wg1 + bg1) . wg2 + bg2 ) ----------
  {
    f32x4 acc[8];
#pragma unroll
    for (int i = 0; i < 8; i++) acc[i] = (f32x4){0.f, 0.f, 0.f, 0.f};
#pragma unroll
    for (int kt = 0; kt < 10; kt++){
      bf16x8 a = *(const bf16x8*)&smA[arow][kt * 32 + kq];
#pragma unroll
      for (int nt = 0; nt < 8; nt++){
        bf16x8 b = *(const bf16x8*)(Wg1p + (((size_t)kt * 128 + nt * 16 + ln) * 4 + q) * 8);
        acc[nt] = __builtin_amdgcn_mfma_f32_16x16x32_bf16(a, b, acc[nt], 0, 0, 0);
      }
    }
    float p0 = 0.f, p1 = 0.f, p2 = 0.f, p3 = 0.f;
#pragma unroll
    for (int nt = 0; nt < 8; nt++){
      int col = nt * 16 + ln;
      float bia = bg1[col];
      float w2 = wg2[col];
      p0 += gelu_f(acc[nt][0] + bia) * w2;
      p1 += gelu_f(acc[nt][1] + bia) * w2;
      p2 += gelu_f(acc[nt][2] + bia) * w2;
      p3 += gelu_f(acc[nt][3] + bia) * w2;
    }
#pragma unroll
    for (int m = 1; m < 16; m <<= 1){
      p0 += __shfl_xor(p0, m); p1 += __shfl_xor(p1, m);
      p2 += __shfl_xor(p2, m); p3 += __shfl_xor(p3, m);
    }
    if (ln == 0){
      float bg = bg2[0];
      smGate[wave * 16 + q * 4 + 0] = 1.f / (1.f + expf(-(p0 + bg)));
      smGate[wave * 16 + q * 4 + 1] = 1.f / (1.f + expf(-(p1 + bg)));
      smGate[wave * 16 + q * 4 + 2] = 1.f / (1.f + expf(-(p2 + bg)));
      smGate[wave * 16 + q * 4 + 3] = 1.f / (1.f + expf(-(p3 + bg)));
    }
  }

  // ---------- message layer 1: tmp = gelu(A[:,128:320]@Wm1 + bm1) -> smT (bf16) ----------
  {
    f32x4 acc[8];
#pragma unroll
    for (int i = 0; i < 8; i++) acc[i] = (f32x4){0.f, 0.f, 0.f, 0.f};
#pragma unroll
    for (int kt = 0; kt < 6; kt++){
      bf16x8 a = *(const bf16x8*)&smA[arow][128 + kt * 32 + kq];
#pragma unroll
      for (int nt = 0; nt < 8; nt++){
        bf16x8 b = *(const bf16x8*)(Wm1p + (((size_t)kt * 128 + nt * 16 + ln) * 4 + q) * 8);
        acc[nt] = __builtin_amdgcn_mfma_f32_16x16x32_bf16(a, b, acc[nt], 0, 0, 0);
      }
    }
#pragma unroll
    for (int nt = 0; nt < 8; nt++){
      int col = nt * 16 + ln;
      float bia = bm1[col];
#pragma unroll
      for (int r = 0; r < 4; r++){
        smT[wave * 16 + q * 4 + r][col] = f2bf(gelu_f(acc[nt][r] + bia));
      }
    }
  }
  // per-wave smT write->read: DS ops are in-order within a wave; no barrier needed.

  // ---------- message layer 2 + gate*msg + store + scatter ----------
  {
    f32x4 acc[8];
#pragma unroll
    for (int i = 0; i < 8; i++) acc[i] = (f32x4){0.f, 0.f, 0.f, 0.f};
#pragma unroll
    for (int kt = 0; kt < 4; kt++){
      bf16x8 a = *(const bf16x8*)&smT[arow][kt * 32 + kq];
#pragma unroll
      for (int nt = 0; nt < 8; nt++){
        bf16x8 b = *(const bf16x8*)(Wm2p + (((size_t)kt * 128 + nt * 16 + ln) * 4 + q) * 8);
        acc[nt] = __builtin_amdgcn_mfma_f32_16x16x32_bf16(a, b, acc[nt], 0, 0, 0);
      }
    }
#pragma unroll
    for (int nt = 0; nt < 8; nt++){
      int col = nt * 16 + ln;
      float bia = bm2[col];
#pragma unroll
      for (int r = 0; r < 4; r++){
        int row = wave * 16 + q * 4 + r;
        float val = smGate[row] * (acc[nt][r] + bia);
        out_e[(size_t)(e0 + row) * 128 + col] = val;
        atomicAdd(&agg[(size_t)smDst[row] * 128 + col], val);
      }
    }
  }
}

// ---------------- fused node kernel: 32 nodes/block ----------------
__global__ __launch_bounds__(256, 2) void node_kernel(
    const float* __restrict__ x, const unsigned short* __restrict__ h_bf,
    const float* __restrict__ agg, const float* __restrict__ deg,
    const unsigned short* __restrict__ Wselfp, const float* __restrict__ bself,
    const unsigned short* __restrict__ Waggp, const float* __restrict__ bagg,
    const float* __restrict__ ln2g, const float* __restrict__ ln2b,
    const unsigned short* __restrict__ Wf1p, const float* __restrict__ bf1,
    const unsigned short* __restrict__ Wf2p, const float* __restrict__ bf2,
    float* __restrict__ out, int n)
{
  __shared__ unsigned short smH[32][136];  // h bf16; later reused as ffn_in bf16
  __shared__ unsigned short smG[32][136];  // agg/deg bf16
  __shared__ float smO[32][132];           // out1 = x + update (fp32, kept for residual)
  __shared__ unsigned short smU[32][264];  // gelu(ffn1) bf16

  const int t = threadIdx.x;
  const int n0 = blockIdx.x * 32;

  {
    const int r = t >> 3, i = t & 7;   // 8 threads/row, 16 cols each
    int gr = n0 + r; if (gr >= n) gr = n - 1;
    const uint4* hp = (const uint4*)(h_bf + (size_t)gr * 128 + i * 16);
    uint4* dp = (uint4*)&smH[r][i * 16];
    dp[0] = hp[0]; dp[1] = hp[1];
    float sc = 1.f / fmaxf(deg[gr], 1.f);
    const float4* ap = (const float4*)(agg + (size_t)gr * 128 + i * 16);
#pragma unroll
    for (int k2 = 0; k2 < 4; k2++){
      float4 f = ap[k2];
      ushort4 u; u.x = f2bf(f.x * sc); u.y = f2bf(f.y * sc); u.z = f2bf(f.z * sc); u.w = f2bf(f.w * sc);
      *(ushort4*)&smG[r][i * 16 + k2 * 4] = u;
    }
  }
  __syncthreads();

  const int wave = t >> 6, lane = t & 63;
  const int q = lane >> 4, ln = lane & 15;
  const int mtile = wave >> 1;        // 2 row-tiles of 16
  const int cg = wave & 1;            // column group
  const int arow = mtile * 16 + ln;
  const int kq = q * 8;

  // ---------- update = h@Wself + agg@Wagg ----------
  f32x4 acc[4];
#pragma unroll
  for (int i = 0; i < 4; i++) acc[i] = (f32x4){0.f, 0.f, 0.f, 0.f};
#pragma unroll
  for (int kt = 0; kt < 4; kt++){
    bf16x8 a = *(const bf16x8*)&smH[arow][kt * 32 + kq];
#pragma unroll
    for (int j = 0; j < 4; j++){
      int col = (cg * 4 + j) * 16 + ln;
      bf16x8 b = *(const bf16x8*)(Wselfp + (((size_t)kt * 128 + col) * 4 + q) * 8);
      acc[j] = __builtin_amdgcn_mfma_f32_16x16x32_bf16(a, b, acc[j], 0, 0, 0);
    }
  }
#pragma unroll
  for (int kt = 0; kt < 4; kt++){
    bf16x8 a = *(const bf16x8*)&smG[arow][kt * 32 + kq];
#pragma unroll
    for (int j = 0; j < 4; j++){
      int col = (cg * 4 + j) * 16 + ln;
      bf16x8 b = *(const bf16x8*)(Waggp + (((size_t)kt * 128 + col) * 4 + q) * 8);
      acc[j] = __builtin_amdgcn_mfma_f32_16x16x32_bf16(a, b, acc[j], 0, 0, 0);
    }
  }
  // out1 = x + update + biases -> smO
#pragma unroll
  for (int j = 0; j < 4; j++){
    int col = (cg * 4 + j) * 16 + ln;
    float bia = bself[col] + bagg[col];
#pragma unroll
    for (int r = 0; r < 4; r++){
      int row = mtile * 16 + q * 4 + r;
      int gr = n0 + row; if (gr >= n) gr = n - 1;
      smO[row][col] = x[(size_t)gr * 128 + col] + acc[j][r] + bia;
    }
  }
  __syncthreads();

  // ---------- LN2 -> ffn_in (bf16 into smH, reuse) ----------
  {
    const int r = t >> 3, i = t & 7;
    float v[16];
    float s = 0.f, s2 = 0.f;
    const float4* op = (const float4*)&smO[r][i * 16];
#pragma unroll
    for (int k2 = 0; k2 < 4; k2++){
      float4 f = op[k2];
      v[k2 * 4 + 0] = f.x; v[k2 * 4 + 1] = f.y; v[k2 * 4 + 2] = f.z; v[k2 * 4 + 3] = f.w;
      s += f.x + f.y + f.z + f.w;
      s2 += f.x * f.x + f.y * f.y + f.z * f.z + f.w * f.w;
    }
#pragma unroll
    for (int m = 1; m < 8; m <<= 1){ s += __shfl_xor(s, m); s2 += __shfl_xor(s2, m); }
    float mu = s * (1.f / 128.f);
    float var = s2 * (1.f / 128.f) - mu * mu;
    float rs = rsqrtf(var + 1e-5f);
#pragma unroll
    for (int c2 = 0; c2 < 16; c2++){
      int col = i * 16 + c2;
      smH[r][col] = f2bf((v[c2] - mu) * rs * ln2g[col] + ln2b[col]);
    }
  }
  __syncthreads();

  // ---------- FFN up: gelu(ffn_in@Wf1 + bf1) -> smU (bf16, N=256) ----------
  {
    f32x4 au[8];
#pragma unroll
    for (int i = 0; i < 8; i++) au[i] = (f32x4){0.f, 0.f, 0.f, 0.f};
#pragma unroll
    for (int kt = 0; kt < 4; kt++){
      bf16x8 a = *(const bf16x8*)&smH[arow][kt * 32 + kq];
#pragma unroll
      for (int j = 0; j < 8; j++){
        int col = (cg * 8 + j) * 16 + ln;
        bf16x8 b = *(const bf16x8*)(Wf1p + (((size_t)kt * 256 + col) * 4 + q) * 8);
        au[j] = __builtin_amdgcn_mfma_f32_16x16x32_bf16(a, b, au[j], 0, 0, 0);
      }
    }
#pragma unroll
    for (int j = 0; j < 8; j++){
      int col = (cg * 8 + j) * 16 + ln;
      float bia = bf1[col];
#pragma unroll
      for (int r = 0; r < 4; r++){
        smU[mtile * 16 + q * 4 + r][col] = f2bf(gelu_f(au[j][r] + bia));
      }
    }
  }
  __syncthreads();

  // ---------- FFN down + residual + store ----------
  {
    f32x4 a2[4];
#pragma unroll
    for (int i = 0; i < 4; i++) a2[i] = (f32x4){0.f, 0.f, 0.f, 0.f};
#pragma unroll
    for (int kt = 0; kt < 8; kt++){
      bf16x8 a = *(const bf16x8*)&smU[arow][kt * 32 + kq];
#pragma unroll
      for (int j = 0; j < 4; j++){
        int col = (cg * 4 + j) * 16 + ln;
        bf16x8 b = *(const bf16x8*)(Wf2p + (((size_t)kt * 128 + col) * 4 + q) * 8);
        a2[j] = __builtin_amdgcn_mfma_f32_16x16x32_bf16(a, b, a2[j], 0, 0, 0);
      }
    }
#pragma unroll
    for (int j = 0; j < 4; j++){
      int col = (cg * 4 + j) * 16 + ln;
      float bia = bf2[col];
#pragma unroll
      for (int r = 0; r < 4; r++){
        int row = mtile * 16 + q * 4 + r;
        int gr = n0 + row;
        if (gr < n) out[(size_t)gr * 128 + col] = smO[row][col] + a2[j][r] + bia;
      }
    }
  }
}

extern "C" void kernel_launch(void* const* d_in, const int* in_sizes, int n_in,
                              void* d_out, int out_size, void* d_ws, size_t ws_size,
                              hipStream_t stream){
  const float* x     = (const float*)d_in[0];
  const int*   esrc  = (const int*)d_in[1];
  const int*   edst  = (const int*)d_in[2];
  const float* eemb  = (const float*)d_in[3];
  const float* ln1g  = (const float*)d_in[4];
  const float* ln1b  = (const float*)d_in[5];
  const float* Wself = (const float*)d_in[6];
  const float* bself = (const float*)d_in[7];
  const float* Wm1   = (const float*)d_in[8];
  const float* bm1   = (const float*)d_in[9];
  const float* Wm2   = (const float*)d_in[10];
  const float* bm2   = (const float*)d_in[11];
  const float* Wg1   = (const float*)d_in[12];
  const float* bg1   = (const float*)d_in[13];
  const float* wg2   = (const float*)d_in[14];
  const float* bg2   = (const float*)d_in[15];
  const float* Wagg  = (const float*)d_in[16];
  const float* bagg  = (const float*)d_in[17];
  const float* ln2g  = (const float*)d_in[18];
  const float* ln2b  = (const float*)d_in[19];
  const float* Wf1   = (const float*)d_in[20];
  const float* bf1   = (const float*)d_in[21];
  const float* Wf2   = (const float*)d_in[22];
  const float* bf2   = (const float*)d_in[23];

  char* ws = (char*)d_ws;
  float* agg = (float*)(ws + 0);                              // 25,600,000 B
  float* deg = (float*)(ws + 25600000);                       //    200,000 B
  unsigned short* h_bf = (unsigned short*)(ws + 25800000);    // 12,800,000 B
  unsigned short* Wselfp = (unsigned short*)(ws + 38600000);
  unsigned short* Wm1p  = Wselfp + 16384;
  unsigned short* Wm2p  = Wm1p + 24576;
  unsigned short* Wg1p  = Wm2p + 16384;
  unsigned short* Waggp = Wg1p + 40960;
  unsigned short* Wf1p  = Waggp + 16384;
  unsigned short* Wf2p  = Wf1p + 32768;

  // zero agg + deg (poisoned each run)
  hipMemsetAsync(agg, 0, 25600000 + 200000, stream);

  pack_kernel<<<64, 256, 0, stream>>>(Wself, Wselfp, 128, 128);
  pack_kernel<<<96, 256, 0, stream>>>(Wm1, Wm1p, 192, 128);
  pack_kernel<<<64, 256, 0, stream>>>(Wm2, Wm2p, 128, 128);
  pack_kernel<<<160, 256, 0, stream>>>(Wg1, Wg1p, 320, 128);
  pack_kernel<<<64, 256, 0, stream>>>(Wagg, Waggp, 128, 128);
  pack_kernel<<<128, 256, 0, stream>>>(Wf1, Wf1p, 128, 256);
  pack_kernel<<<128, 256, 0, stream>>>(Wf2, Wf2p, 256, 128);

  ln1_kernel<<<12500, 256, 0, stream>>>(x, ln1g, ln1b, h_bf, N_NODES);

  float* out_nodes = (float*)d_out;
  float* out_edges = out_nodes + (size_t)N_NODES * 128;

  edge_kernel<<<N_EDGES / 64, 256, 0, stream>>>(h_bf, esrc, edst, eemb,
      Wm1p, bm1, Wm2p, bm2, Wg1p, bg1, wg2, bg2, out_edges, agg, deg);

  node_kernel<<<(N_NODES + 31) / 32, 256, 0, stream>>>(x, h_bf, agg, deg,
      Wselfp, bself, Waggp, bagg, ln2g, ln2b, Wf1p, bf1, Wf2p, bf2, out_nodes, N_NODES);
}

// Round 2
// 953.817 us; speedup vs baseline: 1.2052x; 1.2052x over previous
//
#include <hip/hip_runtime.h>
#include <math.h>

#define N_NODES 50000
#define N_EDGES 600000
#define NTILES (N_EDGES / 64)

typedef __attribute__((ext_vector_type(8))) short bf16x8;
typedef __attribute__((ext_vector_type(4))) float f32x4;

__device__ __forceinline__ unsigned short f2bf(float f){
  union { float f; unsigned int u; } v; v.f = f;
  unsigned int u = v.u;
  unsigned int r = (u + 0x7fffu + ((u >> 16) & 1u)) >> 16;
  return (unsigned short)r;
}
__device__ __forceinline__ float gelu_f(float x){
  return 0.5f * x * (1.0f + erff(x * 0.70710678118654752440f));
}

// ---------------- weight packing: W[K][N] fp32 -> bf16 fragments ----------------
// out[((kt*N + n)*4 + q)*8 + j] = bf16(W[(kt*32 + q*8 + j)*N + n])
__global__ void pack_kernel(const float* __restrict__ W, unsigned short* __restrict__ out,
                            int K, int N){
  int id = blockIdx.x * 256 + threadIdx.x;
  if (id >= K * N) return;
  int j = id & 7;
  int q = (id >> 3) & 3;
  int rest = id >> 5;
  int n = rest % N;
  int kt = rest / N;
  int k = kt * 32 + q * 8 + j;
  out[id] = f2bf(W[(size_t)k * N + n]);
}

// ---------------- LN1: h = LN(x)*g+b, stored bf16 ----------------
__global__ __launch_bounds__(256) void ln1_kernel(const float* __restrict__ x,
                                                  const float* __restrict__ g,
                                                  const float* __restrict__ b,
                                                  unsigned short* __restrict__ h_bf, int n){
  int row = blockIdx.x * 4 + (threadIdx.x >> 6);
  if (row >= n) return;
  int lane = threadIdx.x & 63;
  const float* xr = x + (size_t)row * 128;
  float2 v = *(const float2*)(xr + lane * 2);
  float s = v.x + v.y;
  float s2 = v.x * v.x + v.y * v.y;
#pragma unroll
  for (int off = 32; off; off >>= 1){ s += __shfl_xor(s, off); s2 += __shfl_xor(s2, off); }
  float mu = s * (1.f / 128.f);
  float var = s2 * (1.f / 128.f) - mu * mu;
  float rs = rsqrtf(var + 1e-5f);
  int c = lane * 2;
  ushort2 o;
  o.x = f2bf((v.x - mu) * rs * g[c] + b[c]);
  o.y = f2bf((v.y - mu) * rs * g[c + 1] + b[c + 1]);
  *(ushort2*)(h_bf + (size_t)row * 128 + c) = o;
}

// ---------------- persistent column-split edge kernel ----------------
// 512 blocks grid-stride over 9375 tiles of 64 edges. Wave w owns output
// columns [32w, 32w+32) for ALL 64 rows; its weight slices (40 bf16x8 = 160
// VGPRs) are loaded ONCE per block — kills the 6 GB/launch L2 weight stream.
__global__ __launch_bounds__(256, 2) void edge_kernel(
    const unsigned short* __restrict__ h_bf,
    const int* __restrict__ esrc, const int* __restrict__ edst,
    const float* __restrict__ emb,
    const unsigned short* __restrict__ Wm1p, const float* __restrict__ bm1,
    const unsigned short* __restrict__ Wm2p, const float* __restrict__ bm2,
    const unsigned short* __restrict__ Wg1p, const float* __restrict__ bg1,
    const float* __restrict__ wg2, const float* __restrict__ bg2,
    float* __restrict__ out_e, float* __restrict__ agg, float* __restrict__ deg)
{
  // A = [hd(0:128) | hs(128:256) | emb(256:320)], bf16, stride 328 (2-way banks, free)
  __shared__ unsigned short smA[64][328];
  __shared__ unsigned short smT[64][136];
  __shared__ float smGP[4][64];
  __shared__ float smGate[64];
  __shared__ int smDst[64];

  const int t = threadIdx.x;
  const int wave = t >> 6, lane = t & 63;
  const int q = lane >> 4, ln = lane & 15;
  const int kq = q * 8;

  // ---- per-wave weight slices in registers (loaded once) ----
  bf16x8 wg[10][2], w1[6][2], w2[4][2];
  float bg1r[2], wg2r[2], bm1r[2], bm2r[2];
#pragma unroll
  for (int j = 0; j < 2; j++){
    const int col = wave * 32 + j * 16 + ln;
    bg1r[j] = bg1[col]; wg2r[j] = wg2[col]; bm1r[j] = bm1[col]; bm2r[j] = bm2[col];
#pragma unroll
    for (int kt = 0; kt < 10; kt++) wg[kt][j] = *(const bf16x8*)(Wg1p + (((size_t)kt * 128 + col) * 4 + q) * 8);
#pragma unroll
    for (int kt = 0; kt < 6; kt++)  w1[kt][j] = *(const bf16x8*)(Wm1p + (((size_t)kt * 128 + col) * 4 + q) * 8);
#pragma unroll
    for (int kt = 0; kt < 4; kt++)  w2[kt][j] = *(const bf16x8*)(Wm2p + (((size_t)kt * 128 + col) * 4 + q) * 8);
  }
  const float bg2v = bg2[0];
  const int r4 = t >> 2, i4 = t & 3;   // staging: 4 threads per edge row

  for (int tile = blockIdx.x; tile < NTILES; tile += gridDim.x){
    const int e0 = tile * 64;
    __syncthreads();   // prior iteration's smT/smGate/smDst consumers done

    // ---- stage A + dst ----
    {
      const int e = e0 + r4;
      const int ds = edst[e], ss = esrc[e];
      if (i4 == 0){ smDst[r4] = ds; atomicAdd(&deg[ds], 1.0f); }
      const uint4* hdp = (const uint4*)(h_bf + (size_t)ds * 128 + i4 * 32);
      const uint4* hsp = (const uint4*)(h_bf + (size_t)ss * 128 + i4 * 32);
      uint4* a0 = (uint4*)&smA[r4][i4 * 32];
      uint4* a1 = (uint4*)&smA[r4][128 + i4 * 32];
#pragma unroll
      for (int k2 = 0; k2 < 4; k2++){ a0[k2] = hdp[k2]; a1[k2] = hsp[k2]; }
      const float4* ep = (const float4*)(emb + (size_t)e * 64 + i4 * 16);
#pragma unroll
      for (int k2 = 0; k2 < 4; k2++){
        float4 f = ep[k2];
        ushort4 u; u.x = f2bf(f.x); u.y = f2bf(f.y); u.z = f2bf(f.z); u.w = f2bf(f.w);
        *(ushort4*)&smA[r4][256 + i4 * 16 + k2 * 4] = u;
      }
    }
    __syncthreads();

    // ---- gate: partial over this wave's 32 cols ----
    {
      f32x4 acc[4][2];
#pragma unroll
      for (int rt = 0; rt < 4; rt++)
#pragma unroll
        for (int j = 0; j < 2; j++) acc[rt][j] = (f32x4){0.f, 0.f, 0.f, 0.f};
#pragma unroll
      for (int kt = 0; kt < 10; kt++){
        bf16x8 a[4];
#pragma unroll
        for (int rt = 0; rt < 4; rt++) a[rt] = *(const bf16x8*)&smA[rt * 16 + ln][kt * 32 + kq];
#pragma unroll
        for (int rt = 0; rt < 4; rt++)
#pragma unroll
          for (int j = 0; j < 2; j++)
            acc[rt][j] = __builtin_amdgcn_mfma_f32_16x16x32_bf16(a[rt], wg[kt][j], acc[rt][j], 0, 0, 0);
      }
      float p[4][4];
#pragma unroll
      for (int rt = 0; rt < 4; rt++)
#pragma unroll
        for (int r = 0; r < 4; r++)
          p[rt][r] = gelu_f(acc[rt][0][r] + bg1r[0]) * wg2r[0]
                   + gelu_f(acc[rt][1][r] + bg1r[1]) * wg2r[1];
#pragma unroll
      for (int m = 1; m < 16; m <<= 1){
#pragma unroll
        for (int rt = 0; rt < 4; rt++)
#pragma unroll
          for (int r = 0; r < 4; r++) p[rt][r] += __shfl_xor(p[rt][r], m);
      }
      if (ln == 0){
#pragma unroll
        for (int rt = 0; rt < 4; rt++)
#pragma unroll
          for (int r = 0; r < 4; r++) smGP[wave][rt * 16 + q * 4 + r] = p[rt][r];
      }
    }
    __syncthreads();
    if (t < 64)
      smGate[t] = 1.f / (1.f + expf(-(smGP[0][t] + smGP[1][t] + smGP[2][t] + smGP[3][t] + bg2v)));

    // ---- msg layer 1 -> smT (this wave's 32 cols, all 64 rows) ----
    {
      f32x4 acc[4][2];
#pragma unroll
      for (int rt = 0; rt < 4; rt++)
#pragma unroll
        for (int j = 0; j < 2; j++) acc[rt][j] = (f32x4){0.f, 0.f, 0.f, 0.f};
#pragma unroll
      for (int kt = 0; kt < 6; kt++){
        bf16x8 a[4];
#pragma unroll
        for (int rt = 0; rt < 4; rt++) a[rt] = *(const bf16x8*)&smA[rt * 16 + ln][128 + kt * 32 + kq];
#pragma unroll
        for (int rt = 0; rt < 4; rt++)
#pragma unroll
          for (int j = 0; j < 2; j++)
            acc[rt][j] = __builtin_amdgcn_mfma_f32_16x16x32_bf16(a[rt], w1[kt][j], acc[rt][j], 0, 0, 0);
      }
#pragma unroll
      for (int rt = 0; rt < 4; rt++)
#pragma unroll
        for (int j = 0; j < 2; j++){
          const int col = wave * 32 + j * 16 + ln;
          const float bia = bm1r[j];
#pragma unroll
          for (int r = 0; r < 4; r++)
            smT[rt * 16 + q * 4 + r][col] = f2bf(gelu_f(acc[rt][j][r] + bia));
        }
    }
    __syncthreads();   // smT + smGate ready

    // ---- msg layer 2 + gate*msg + store + scatter ----
    {
      f32x4 acc[4][2];
#pragma unroll
      for (int rt = 0; rt < 4; rt++)
#pragma unroll
        for (int j = 0; j < 2; j++) acc[rt][j] = (f32x4){0.f, 0.f, 0.f, 0.f};
#pragma unroll
      for (int kt = 0; kt < 4; kt++){
        bf16x8 a[4];
#pragma unroll
        for (int rt = 0; rt < 4; rt++) a[rt] = *(const bf16x8*)&smT[rt * 16 + ln][kt * 32 + kq];
#pragma unroll
        for (int rt = 0; rt < 4; rt++)
#pragma unroll
          for (int j = 0; j < 2; j++)
            acc[rt][j] = __builtin_amdgcn_mfma_f32_16x16x32_bf16(a[rt], w2[kt][j], acc[rt][j], 0, 0, 0);
      }
#pragma unroll
      for (int rt = 0; rt < 4; rt++)
#pragma unroll
        for (int j = 0; j < 2; j++){
          const int col = wave * 32 + j * 16 + ln;
          const float bia = bm2r[j];
#pragma unroll
          for (int r = 0; r < 4; r++){
            const int row = rt * 16 + q * 4 + r;
            const float val = smGate[row] * (acc[rt][j][r] + bia);
            out_e[(size_t)(e0 + row) * 128 + col] = val;
            atomicAdd(&agg[(size_t)smDst[row] * 128 + col], val);
          }
        }
    }
  }
}

// ---------------- fused node kernel: 32 nodes/block ----------------
__global__ __launch_bounds__(256, 2) void node_kernel(
    const float* __restrict__ x, const unsigned short* __restrict__ h_bf,
    const float* __restrict__ agg, const float* __restrict__ deg,
    const unsigned short* __restrict__ Wselfp, const float* __restrict__ bself,
    const unsigned short* __restrict__ Waggp, const float* __restrict__ bagg,
    const float* __restrict__ ln2g, const float* __restrict__ ln2b,
    const unsigned short* __restrict__ Wf1p, const float* __restrict__ bf1,
    const unsigned short* __restrict__ Wf2p, const float* __restrict__ bf2,
    float* __restrict__ out, int n)
{
  __shared__ unsigned short smH[32][136];
  __shared__ unsigned short smG[32][136];
  __shared__ float smO[32][132];
  __shared__ unsigned short smU[32][264];

  const int t = threadIdx.x;
  const int n0 = blockIdx.x * 32;

  {
    const int r = t >> 3, i = t & 7;
    int gr = n0 + r; if (gr >= n) gr = n - 1;
    const uint4* hp = (const uint4*)(h_bf + (size_t)gr * 128 + i * 16);
    uint4* dp = (uint4*)&smH[r][i * 16];
    dp[0] = hp[0]; dp[1] = hp[1];
    float sc = 1.f / fmaxf(deg[gr], 1.f);
    const float4* ap = (const float4*)(agg + (size_t)gr * 128 + i * 16);
#pragma unroll
    for (int k2 = 0; k2 < 4; k2++){
      float4 f = ap[k2];
      ushort4 u; u.x = f2bf(f.x * sc); u.y = f2bf(f.y * sc); u.z = f2bf(f.z * sc); u.w = f2bf(f.w * sc);
      *(ushort4*)&smG[r][i * 16 + k2 * 4] = u;
    }
  }
  __syncthreads();

  const int wave = t >> 6, lane = t & 63;
  const int q = lane >> 4, ln = lane & 15;
  const int mtile = wave >> 1;
  const int cg = wave & 1;
  const int arow = mtile * 16 + ln;
  const int kq = q * 8;

  f32x4 acc[4];
#pragma unroll
  for (int i = 0; i < 4; i++) acc[i] = (f32x4){0.f, 0.f, 0.f, 0.f};
#pragma unroll
  for (int kt = 0; kt < 4; kt++){
    bf16x8 a = *(const bf16x8*)&smH[arow][kt * 32 + kq];
#pragma unroll
    for (int j = 0; j < 4; j++){
      int col = (cg * 4 + j) * 16 + ln;
      bf16x8 b = *(const bf16x8*)(Wselfp + (((size_t)kt * 128 + col) * 4 + q) * 8);
      acc[j] = __builtin_amdgcn_mfma_f32_16x16x32_bf16(a, b, acc[j], 0, 0, 0);
    }
  }
#pragma unroll
  for (int kt = 0; kt < 4; kt++){
    bf16x8 a = *(const bf16x8*)&smG[arow][kt * 32 + kq];
#pragma unroll
    for (int j = 0; j < 4; j++){
      int col = (cg * 4 + j) * 16 + ln;
      bf16x8 b = *(const bf16x8*)(Waggp + (((size_t)kt * 128 + col) * 4 + q) * 8);
      acc[j] = __builtin_amdgcn_mfma_f32_16x16x32_bf16(a, b, acc[j], 0, 0, 0);
    }
  }
#pragma unroll
  for (int j = 0; j < 4; j++){
    int col = (cg * 4 + j) * 16 + ln;
    float bia = bself[col] + bagg[col];
#pragma unroll
    for (int r = 0; r < 4; r++){
      int row = mtile * 16 + q * 4 + r;
      int gr = n0 + row; if (gr >= n) gr = n - 1;
      smO[row][col] = x[(size_t)gr * 128 + col] + acc[j][r] + bia;
    }
  }
  __syncthreads();

  {
    const int r = t >> 3, i = t & 7;
    float v[16];
    float s = 0.f, s2 = 0.f;
    const float4* op = (const float4*)&smO[r][i * 16];
#pragma unroll
    for (int k2 = 0; k2 < 4; k2++){
      float4 f = op[k2];
      v[k2 * 4 + 0] = f.x; v[k2 * 4 + 1] = f.y; v[k2 * 4 + 2] = f.z; v[k2 * 4 + 3] = f.w;
      s += f.x + f.y + f.z + f.w;
      s2 += f.x * f.x + f.y * f.y + f.z * f.z + f.w * f.w;
    }
#pragma unroll
    for (int m = 1; m < 8; m <<= 1){ s += __shfl_xor(s, m); s2 += __shfl_xor(s2, m); }
    float mu = s * (1.f / 128.f);
    float var = s2 * (1.f / 128.f) - mu * mu;
    float rs = rsqrtf(var + 1e-5f);
#pragma unroll
    for (int c2 = 0; c2 < 16; c2++){
      int col = i * 16 + c2;
      smH[r][col] = f2bf((v[c2] - mu) * rs * ln2g[col] + ln2b[col]);
    }
  }
  __syncthreads();

  {
    f32x4 au[8];
#pragma unroll
    for (int i = 0; i < 8; i++) au[i] = (f32x4){0.f, 0.f, 0.f, 0.f};
#pragma unroll
    for (int kt = 0; kt < 4; kt++){
      bf16x8 a = *(const bf16x8*)&smH[arow][kt * 32 + kq];
#pragma unroll
      for (int j = 0; j < 8; j++){
        int col = (cg * 8 + j) * 16 + ln;
        bf16x8 b = *(const bf16x8*)(Wf1p + (((size_t)kt * 256 + col) * 4 + q) * 8);
        au[j] = __builtin_amdgcn_mfma_f32_16x16x32_bf16(a, b, au[j], 0, 0, 0);
      }
    }
#pragma unroll
    for (int j = 0; j < 8; j++){
      int col = (cg * 8 + j) * 16 + ln;
      float bia = bf1[col];
#pragma unroll
      for (int r = 0; r < 4; r++){
        smU[mtile * 16 + q * 4 + r][col] = f2bf(gelu_f(au[j][r] + bia));
      }
    }
  }
  __syncthreads();

  {
    f32x4 a2[4];
#pragma unroll
    for (int i = 0; i < 4; i++) a2[i] = (f32x4){0.f, 0.f, 0.f, 0.f};
#pragma unroll
    for (int kt = 0; kt < 8; kt++){
      bf16x8 a = *(const bf16x8*)&smU[arow][kt * 32 + kq];
#pragma unroll
      for (int j = 0; j < 4; j++){
        int col = (cg * 4 + j) * 16 + ln;
        bf16x8 b = *(const bf16x8*)(Wf2p + (((size_t)kt * 128 + col) * 4 + q) * 8);
        a2[j] = __builtin_amdgcn_mfma_f32_16x16x32_bf16(a, b, a2[j], 0, 0, 0);
      }
    }
#pragma unroll
    for (int j = 0; j < 4; j++){
      int col = (cg * 4 + j) * 16 + ln;
      float bia = bf2[col];
#pragma unroll
      for (int r = 0; r < 4; r++){
        int row = mtile * 16 + q * 4 + r;
        int gr = n0 + row;
        if (gr < n) out[(size_t)gr * 128 + col] = smO[row][col] + a2[j][r] + bia;
      }
    }
  }
}

extern "C" void kernel_launch(void* const* d_in, const int* in_sizes, int n_in,
                              void* d_out, int out_size, void* d_ws, size_t ws_size,
                              hipStream_t stream){
  const float* x     = (const float*)d_in[0];
  const int*   esrc  = (const int*)d_in[1];
  const int*   edst  = (const int*)d_in[2];
  const float* eemb  = (const float*)d_in[3];
  const float* ln1g  = (const float*)d_in[4];
  const float* ln1b  = (const float*)d_in[5];
  const float* Wself = (const float*)d_in[6];
  const float* bself = (const float*)d_in[7];
  const float* Wm1   = (const float*)d_in[8];
  const float* bm1   = (const float*)d_in[9];
  const float* Wm2   = (const float*)d_in[10];
  const float* bm2   = (const float*)d_in[11];
  const float* Wg1   = (const float*)d_in[12];
  const float* bg1   = (const float*)d_in[13];
  const float* wg2   = (const float*)d_in[14];
  const float* bg2   = (const float*)d_in[15];
  const float* Wagg  = (const float*)d_in[16];
  const float* bagg  = (const float*)d_in[17];
  const float* ln2g  = (const float*)d_in[18];
  const float* ln2b  = (const float*)d_in[19];
  const float* Wf1   = (const float*)d_in[20];
  const float* bf1   = (const float*)d_in[21];
  const float* Wf2   = (const float*)d_in[22];
  const float* bf2   = (const float*)d_in[23];

  char* ws = (char*)d_ws;
  float* agg = (float*)(ws + 0);                              // 25,600,000 B
  float* deg = (float*)(ws + 25600000);                       //    200,000 B
  unsigned short* h_bf = (unsigned short*)(ws + 25800000);    // 12,800,000 B
  unsigned short* Wselfp = (unsigned short*)(ws + 38600000);
  unsigned short* Wm1p  = Wselfp + 16384;
  unsigned short* Wm2p  = Wm1p + 24576;
  unsigned short* Wg1p  = Wm2p + 16384;
  unsigned short* Waggp = Wg1p + 40960;
  unsigned short* Wf1p  = Waggp + 16384;
  unsigned short* Wf2p  = Wf1p + 32768;

  hipMemsetAsync(agg, 0, 25600000 + 200000, stream);

  pack_kernel<<<64, 256, 0, stream>>>(Wself, Wselfp, 128, 128);
  pack_kernel<<<96, 256, 0, stream>>>(Wm1, Wm1p, 192, 128);
  pack_kernel<<<64, 256, 0, stream>>>(Wm2, Wm2p, 128, 128);
  pack_kernel<<<160, 256, 0, stream>>>(Wg1, Wg1p, 320, 128);
  pack_kernel<<<64, 256, 0, stream>>>(Wagg, Waggp, 128, 128);
  pack_kernel<<<128, 256, 0, stream>>>(Wf1, Wf1p, 128, 256);
  pack_kernel<<<128, 256, 0, stream>>>(Wf2, Wf2p, 256, 128);

  ln1_kernel<<<12500, 256, 0, stream>>>(x, ln1g, ln1b, h_bf, N_NODES);

  float* out_nodes = (float*)d_out;
  float* out_edges = out_nodes + (size_t)N_NODES * 128;

  edge_kernel<<<512, 256, 0, stream>>>(h_bf, esrc, edst, eemb,
      Wm1p, bm1, Wm2p, bm2, Wg1p, bg1, wg2, bg2, out_edges, agg, deg);

  node_kernel<<<(N_NODES + 31) / 32, 256, 0, stream>>>(x, h_bf, agg, deg,
      Wselfp, bself, Waggp, bagg, ln2g, ln2b, Wf1p, bf1, Wf2p, bf2, out_nodes, N_NODES);
}